// Round 1
// baseline (611.722 us; speedup 1.0000x reference)
//
#include <hip/hip_runtime.h>

// CoscamLoss: B=4096 rows, C=16384 cols.
// loss = mean_rows [ logsumexp_j(out[j]) - out[t] ]
//   out[j] = 16 * ( j==t ? gt - 0.1
//                        : (pos[j]==1 && x[j] >= gt) ? 1.012*x[j] + 0.012
//                                                    : x[j] )
// Memory-bound: 512 MB read / call -> ~81 us floor at 6.3 TB/s.

#define B_ 4096
#define C_ 16384

__global__ __launch_bounds__(256) void coscam_loss_kernel(
    const float* __restrict__ inputs,
    const int*   __restrict__ targets,
    const float* __restrict__ pos_mask,
    float*       __restrict__ out)
{
    const int row = blockIdx.x;
    const int tid = threadIdx.x;

    __shared__ float s_gt;
    __shared__ int   s_t;
    __shared__ float red_m[4];
    __shared__ float red_s[4];

    if (tid == 0) {
        int t = targets[row];
        s_t  = t;
        s_gt = inputs[(size_t)row * C_ + t];
    }
    __syncthreads();

    const float gt = s_gt;
    const int   t  = s_t;
    const float out_t = 16.0f * (gt - 0.1f);

    const float* __restrict__ rin = inputs   + (size_t)row * C_;
    const float* __restrict__ rpm = pos_mask + (size_t)row * C_;

    // online logsumexp state
    float m = -3.0e38f;
    float s = 0.0f;

    // 256 threads * float4 = 1024 elems/iter -> 16 iters over C=16384
    for (int c = tid * 4; c < C_; c += 256 * 4) {
        const float4 x4 = *(const float4*)(rin + c);
        const float4 p4 = *(const float4*)(rpm + c);
        #pragma unroll
        for (int k = 0; k < 4; ++k) {
            const float x = (&x4.x)[k];
            const float p = (&p4.x)[k];
            const bool hard = (p > 0.5f) && (x >= gt);
            float v = hard ? fmaf(1.012f, x, 0.012f) : x;
            v *= 16.0f;
            if (c + k == t) v = out_t;   // restore gt, subtract margin at target
            // online update: common path (v <= m) costs 1 exp
            if (v <= m) {
                s += __expf(v - m);
            } else {
                s = fmaf(s, __expf(m - v), 1.0f);
                m = v;
            }
        }
    }

    // wave-64 butterfly-ish shuffle reduce of (m, s)
    #pragma unroll
    for (int off = 32; off > 0; off >>= 1) {
        const float om = __shfl_down(m, off);
        const float os = __shfl_down(s, off);
        const float nm = fmaxf(m, om);
        s = s * __expf(m - nm) + os * __expf(om - nm);
        m = nm;
    }

    const int wave = tid >> 6;
    const int lane = tid & 63;
    if (lane == 0) { red_m[wave] = m; red_s[wave] = s; }
    __syncthreads();

    if (tid == 0) {
        m = red_m[0];
        s = red_s[0];
        #pragma unroll
        for (int w = 1; w < 4; ++w) {
            const float om = red_m[w];
            const float os = red_s[w];
            const float nm = fmaxf(m, om);
            s = s * __expf(m - nm) + os * __expf(om - nm);
            m = nm;
        }
        const float loss_row = (__logf(s) + m) - out_t;
        atomicAdd(out, loss_row * (1.0f / (float)B_));
    }
}

extern "C" void kernel_launch(void* const* d_in, const int* in_sizes, int n_in,
                              void* d_out, int out_size, void* d_ws, size_t ws_size,
                              hipStream_t stream) {
    const float* inputs   = (const float*)d_in[0];
    const int*   targets  = (const int*)  d_in[1];
    // d_in[2] = mask (unused by the reference)
    const float* pos_mask = (const float*)d_in[3];
    float* out = (float*)d_out;

    // d_out is poisoned 0xAA before every timed call -> zero it on-stream.
    hipMemsetAsync(out, 0, sizeof(float), stream);

    coscam_loss_kernel<<<dim3(B_), dim3(256), 0, stream>>>(inputs, targets, pos_mask, out);
}

// Round 3
// 597.554 us; speedup vs baseline: 1.0237x; 1.0237x over previous
//
#include <hip/hip_runtime.h>

// CoscamLoss: B=4096 rows, C=16384 cols. One block per row.
// loss = mean_rows [ logsumexp_j(v[j]) - v[t] ]
//   v[j] = 16 * ( j==t ? gt - 0.1
//                      : (pos[j]==1 && x[j] >= gt) ? 1.012*x[j] + 0.012
//                                                  : x[j] )
// R1 post-mortem: branchy online softmax was issue-bound (~84 VALU cyc/elem
// from divergent exec-mask branches). R2: branch-free fixed-shift softmax.
// R2 compile fix: __exp2f clashes with a glibc math macro -> use the raw
// hardware intrinsic __builtin_amdgcn_exp2f (one v_exp_f32, computes 2^x).
// Safety of shift = max(16*(gt-0.1), 40):
//   overflow needs v - shift > 88 -> x > 7.9 (p ~ 1e-15): never.
//   sum >= exp(v_t - shift) and row-max term always representable: log never -inf.
//   terms lost to f32 underflow are < e^-87 relative: negligible vs 1.32 threshold.

#define B_ 4096
#define C_ 16384
#define LOG2E 1.44269504088896340736f

__global__ __launch_bounds__(256, 4) void coscam_loss_kernel(
    const float* __restrict__ inputs,
    const int*   __restrict__ targets,
    const float* __restrict__ pos_mask,
    float*       __restrict__ out)
{
    const int row = blockIdx.x;
    const int tid = threadIdx.x;

    __shared__ float s_gt;
    __shared__ int   s_t;
    __shared__ float red_s[4];

    if (tid == 0) {
        int t = targets[row];
        s_t  = t;
        s_gt = inputs[(size_t)row * C_ + t];
    }
    __syncthreads();

    const float gt    = s_gt;
    const int   t     = s_t;
    const float wt    = gt - 0.1f;            // pre-scale target value
    const float out_t = 16.0f * wt;
    const float shift = fmaxf(out_t, 40.0f);
    const float nshift2 = -shift * LOG2E;     // shift in log2 domain, negated
    // exp(16*w - shift) = exp2(w * 16*log2e + nshift2)
    const float k16l2e = 16.0f * LOG2E;

    const float* __restrict__ rin = inputs   + (size_t)row * C_;
    const float* __restrict__ rpm = pos_mask + (size_t)row * C_;

    float acc0 = 0.0f, acc1 = 0.0f, acc2 = 0.0f, acc3 = 0.0f;

    // 256 threads * float4 = 1024 elems/iter -> 16 iters; unroll 4 so the
    // scheduler keeps 8 dwordx4 loads in flight per wave.
    #pragma unroll 4
    for (int c = tid * 4; c < C_; c += 256 * 4) {
        const float4 x4 = *(const float4*)(rin + c);
        const float4 p4 = *(const float4*)(rpm + c);

        float w0 = ((p4.x > 0.5f) && (x4.x >= gt)) ? fmaf(1.012f, x4.x, 0.012f) : x4.x;
        float w1 = ((p4.y > 0.5f) && (x4.y >= gt)) ? fmaf(1.012f, x4.y, 0.012f) : x4.y;
        float w2 = ((p4.z > 0.5f) && (x4.z >= gt)) ? fmaf(1.012f, x4.z, 0.012f) : x4.z;
        float w3 = ((p4.w > 0.5f) && (x4.w >= gt)) ? fmaf(1.012f, x4.w, 0.012f) : x4.w;

        w0 = (c + 0 == t) ? wt : w0;
        w1 = (c + 1 == t) ? wt : w1;
        w2 = (c + 2 == t) ? wt : w2;
        w3 = (c + 3 == t) ? wt : w3;

        acc0 += __builtin_amdgcn_exp2f(fmaf(w0, k16l2e, nshift2));
        acc1 += __builtin_amdgcn_exp2f(fmaf(w1, k16l2e, nshift2));
        acc2 += __builtin_amdgcn_exp2f(fmaf(w2, k16l2e, nshift2));
        acc3 += __builtin_amdgcn_exp2f(fmaf(w3, k16l2e, nshift2));
    }

    float s = (acc0 + acc1) + (acc2 + acc3);

    // wave-64 shuffle reduce (sum)
    #pragma unroll
    for (int off = 32; off > 0; off >>= 1)
        s += __shfl_down(s, off);

    const int wave = tid >> 6;
    const int lane = tid & 63;
    if (lane == 0) red_s[wave] = s;
    __syncthreads();

    if (tid == 0) {
        const float total = (red_s[0] + red_s[1]) + (red_s[2] + red_s[3]);
        const float loss_row = (__logf(total) + shift) - out_t;
        atomicAdd(out, loss_row * (1.0f / (float)B_));
    }
}

extern "C" void kernel_launch(void* const* d_in, const int* in_sizes, int n_in,
                              void* d_out, int out_size, void* d_ws, size_t ws_size,
                              hipStream_t stream) {
    const float* inputs   = (const float*)d_in[0];
    const int*   targets  = (const int*)  d_in[1];
    // d_in[2] = mask (unused by the reference)
    const float* pos_mask = (const float*)d_in[3];
    float* out = (float*)d_out;

    // d_out is poisoned 0xAA before every timed call -> zero it on-stream.
    (void)hipMemsetAsync(out, 0, sizeof(float), stream);

    coscam_loss_kernel<<<dim3(B_), dim3(256), 0, stream>>>(inputs, targets, pos_mask, out);
}

// Round 4
// 597.438 us; speedup vs baseline: 1.0239x; 1.0002x over previous
//
#include <hip/hip_runtime.h>

// CoscamLoss: B=4096 rows, C=16384 cols. One block (256 thr) per row.
// loss = mean_rows [ logsumexp_j(v[j]) - v[t] ],
//   v[j] = 16 * ( j==t ? gt-0.1 : (pos[j]==1 && x[j]>=gt) ? 1.012x[j]+0.012 : x[j] )
//
// R3 post-mortem: kernel ~150us, outstanding-load-limited (VGPR=12 -> ~3 loads
// in flight/wave -> ~3.5 TB/s by Little's law). R4: fully unroll the 16
// iterations with loads batched into local arrays -> 32 dwordx4 in flight per
// wave (~128 data VGPRs, launch_bounds(256,3) -> 3 waves/SIMD, ~6KB
// outstanding/CU -> ~6 TB/s). Target element handled by exact post-loop
// correction instead of a per-element compare.
//
// Numerics: shift = max(16*(gt-0.1), 40); overflow needs x > 7.9 (never for
// N(0,1) at this size); sum always >= representable row-max term; underflow
// losses < e^-87 relative. Threshold is 1.32 -- huge margin.

#define B_ 4096
#define C_ 16384
#define LOG2E 1.44269504088896340736f

__global__ __launch_bounds__(256, 3) void coscam_loss_kernel(
    const float* __restrict__ inputs,
    const int*   __restrict__ targets,
    const float* __restrict__ pos_mask,
    float*       __restrict__ out)
{
    const int row = blockIdx.x;
    const int tid = threadIdx.x;

    const float* __restrict__ rin = inputs   + (size_t)row * C_;
    const float* __restrict__ rpm = pos_mask + (size_t)row * C_;

    // Wave-uniform broadcast loads (same address across lanes -> one
    // transaction + broadcast). No LDS staging, no barrier before the loop.
    const int   t     = targets[row];
    const float gt    = rin[t];
    const float pos_t = rpm[t];        // for the epilogue correction

    const float wt      = gt - 0.1f;          // pre-scale target value
    const float out_t   = 16.0f * wt;
    const float shift   = fmaxf(out_t, 40.0f);
    const float nshift2 = -shift * LOG2E;     // exp(16w - shift) = exp2(fma(w,16log2e,nshift2))
    const float k16l2e  = 16.0f * LOG2E;

    // ---- batch ALL loads: 16 iters x (x4,p4) = 32 dwordx4 in flight ----
    float4 xs[16], ps[16];
    #pragma unroll
    for (int u = 0; u < 16; ++u) {
        const int c = u * 1024 + tid * 4;
        xs[u] = *(const float4*)(rin + c);
        ps[u] = *(const float4*)(rpm + c);
    }

    float acc0 = 0.0f, acc1 = 0.0f, acc2 = 0.0f, acc3 = 0.0f;
    #pragma unroll
    for (int u = 0; u < 16; ++u) {
        const float4 x4 = xs[u];
        const float4 p4 = ps[u];
        const float w0 = ((p4.x > 0.5f) && (x4.x >= gt)) ? fmaf(1.012f, x4.x, 0.012f) : x4.x;
        const float w1 = ((p4.y > 0.5f) && (x4.y >= gt)) ? fmaf(1.012f, x4.y, 0.012f) : x4.y;
        const float w2 = ((p4.z > 0.5f) && (x4.z >= gt)) ? fmaf(1.012f, x4.z, 0.012f) : x4.z;
        const float w3 = ((p4.w > 0.5f) && (x4.w >= gt)) ? fmaf(1.012f, x4.w, 0.012f) : x4.w;
        acc0 += __builtin_amdgcn_exp2f(fmaf(w0, k16l2e, nshift2));
        acc1 += __builtin_amdgcn_exp2f(fmaf(w1, k16l2e, nshift2));
        acc2 += __builtin_amdgcn_exp2f(fmaf(w2, k16l2e, nshift2));
        acc3 += __builtin_amdgcn_exp2f(fmaf(w3, k16l2e, nshift2));
    }

    float s = (acc0 + acc1) + (acc2 + acc3);

    // wave-64 shuffle reduce (sum)
    #pragma unroll
    for (int off = 32; off > 0; off >>= 1)
        s += __shfl_down(s, off);

    __shared__ float red_s[4];
    const int wave = tid >> 6;
    const int lane = tid & 63;
    if (lane == 0) red_s[wave] = s;
    __syncthreads();

    if (tid == 0) {
        float total = (red_s[0] + red_s[1]) + (red_s[2] + red_s[3]);
        // Exact correction for the target slot: the loop computed it with the
        // generic formula (x[t]==gt so x>=gt is true); replace with wt.
        const float w_wrong = (pos_t > 0.5f) ? fmaf(1.012f, gt, 0.012f) : gt;
        total += __builtin_amdgcn_exp2f(fmaf(wt,      k16l2e, nshift2))
               - __builtin_amdgcn_exp2f(fmaf(w_wrong, k16l2e, nshift2));
        const float loss_row = (__logf(total) + shift) - out_t;
        atomicAdd(out, loss_row * (1.0f / (float)B_));
    }
}

extern "C" void kernel_launch(void* const* d_in, const int* in_sizes, int n_in,
                              void* d_out, int out_size, void* d_ws, size_t ws_size,
                              hipStream_t stream) {
    const float* inputs   = (const float*)d_in[0];
    const int*   targets  = (const int*)  d_in[1];
    // d_in[2] = mask (unused by the reference)
    const float* pos_mask = (const float*)d_in[3];
    float* out = (float*)d_out;

    // d_out is poisoned 0xAA before every timed call -> zero it on-stream.
    (void)hipMemsetAsync(out, 0, sizeof(float), stream);

    coscam_loss_kernel<<<dim3(B_), dim3(256), 0, stream>>>(inputs, targets, pos_mask, out);
}